// Round 6
// baseline (460.929 us; speedup 1.0000x reference)
//
#include <hip/hip_runtime.h>
#include <math.h>

#define CCH 128
#define HH 192
#define WW 192
#define BB 2
#define HW (HH*WW)        // 36864
#define CHW (CCH*HW)      // 4718592
#define BF 128            // B * f*f = 2*64
#define NN 576            // 24*24
#define SH 24

typedef __attribute__((ext_vector_type(8))) short short8;
typedef __attribute__((ext_vector_type(4))) float floatx4;
typedef unsigned int uint32;
typedef unsigned short ushort;

__device__ __forceinline__ unsigned short bf16r(float f) {
    uint32 u = __float_as_uint(f);
    u += 0x7fffu + ((u >> 16) & 1u);
    return (unsigned short)(u >> 16);
}
__device__ __forceinline__ float frombf(ushort u) {
    return __uint_as_float(((uint32)u) << 16);
}

// ---------------- K1: per-batch sum / sumsq reduction ----------------
__global__ __launch_bounds__(256) void k_reduce(const float* __restrict__ x, float* __restrict__ stats) {
    int b = blockIdx.y;
    const float4* p = (const float4*)(x + (size_t)b*CHW) + (size_t)blockIdx.x*4096;
    float s = 0.f, sq = 0.f;
#pragma unroll
    for (int k = 0; k < 16; ++k) {
        float4 v = p[threadIdx.x + 256*k];
        s  += v.x + v.y + v.z + v.w;
        sq += v.x*v.x + v.y*v.y + v.z*v.z + v.w*v.w;
    }
    for (int off = 32; off; off >>= 1) { s += __shfl_down(s, off); sq += __shfl_down(sq, off); }
    __shared__ float ls[4], lq[4];
    int wave = threadIdx.x >> 6, lane = threadIdx.x & 63;
    if (lane == 0) { ls[wave] = s; lq[wave] = sq; }
    __syncthreads();
    if (threadIdx.x == 0) {
        atomicAdd(&stats[2*b],   ls[0]+ls[1]+ls[2]+ls[3]);
        atomicAdd(&stats[2*b+1], lq[0]+lq[1]+lq[2]+lq[3]);
    }
}

__global__ void k_finalize(float* stats) {
    int b = threadIdx.x;
    if (b < BB) {
        float s = stats[2*b], sq = stats[2*b+1];
        float mean = s / (float)CHW;
        float var = sq / (float)CHW - mean*mean;
        stats[4 + 2*b] = mean;
        stats[5 + 2*b] = rsqrtf(var + 1e-5f);
    }
}

// ---------------- K3: x -> V_t bf16 [Bf,C,N] and Xn fp32 [Bf,N,C] ----------------
__global__ __launch_bounds__(256) void k_unshuffle(const float* __restrict__ x, const float* __restrict__ stats,
                                                   ushort* __restrict__ Vt, float* __restrict__ Xn) {
    __shared__ float t[128][65];
    int x0 = blockIdx.x * 64;
    int y  = blockIdx.y;
    int b  = blockIdx.z;
    float mean = stats[4+2*b], istd = stats[5+2*b];
    const float* src = x + (size_t)b*CHW + (size_t)y*WW + x0;
#pragma unroll
    for (int k = 0; k < 32; ++k) {
        int idx = threadIdx.x + 256*k;
        int c = idx >> 6, xl = idx & 63;
        t[c][xl] = src[(size_t)c*HW + xl];
    }
    __syncthreads();
    int i = y >> 3, dy = y & 7;
#pragma unroll
    for (int k = 0; k < 32; ++k) {
        int idx = threadIdx.x + 256*k;
        int c = idx & 127, xl = idx >> 7;
        int xx = x0 + xl;
        int j = xx >> 3, dx = xx & 7;
        int bf = (b << 6) + (dy << 3) + dx;
        int n = i*SH + j;
        float v = t[c][xl];
        Vt[((size_t)bf*CCH + c)*NN + n] = bf16r(v);
        Xn[((size_t)bf*NN + n)*CCH + c] = (v - mean) * istd;
    }
}

// ---------------- K4: qkn(bf16) = normalize_rows(Xn @ wqk) ----------------
__global__ __launch_bounds__(256) void k_qk(const float* __restrict__ Xn, const float* __restrict__ wqk,
                                            ushort* __restrict__ qkn) {
    __shared__ float Qs[64][129];
    __shared__ float ssb[64][4];
    int bid = blockIdx.x;           // 0..1151
    int bf = bid / 9, tile = bid % 9;
    int n0 = tile * 64;
    const float* src = Xn + ((size_t)bf*NN + n0)*CCH;
#pragma unroll
    for (int k = 0; k < 32; ++k) {
        int idx = threadIdx.x + 256*k;
        Qs[idx >> 7][idx & 127] = src[idx];
    }
    __syncthreads();
    int lane = threadIdx.x & 63;
    int wave = __builtin_amdgcn_readfirstlane(threadIdx.x >> 6);
    float acc[32];
#pragma unroll
    for (int k = 0; k < 32; ++k) acc[k] = 0.f;
    const float* wp = wqk + wave*32;
    for (int c = 0; c < 128; ++c) {
        float qv = Qs[lane][c];
#pragma unroll
        for (int k = 0; k < 32; ++k) acc[k] += qv * wp[c*128 + k];
    }
    float ss = 0.f;
#pragma unroll
    for (int k = 0; k < 32; ++k) ss += acc[k]*acc[k];
    ssb[lane][wave] = ss;
    __syncthreads();
    float tot = ssb[lane][0]+ssb[lane][1]+ssb[lane][2]+ssb[lane][3];
    float f = 1.f / (sqrtf(tot) + 1e-8f);
    ushort* dst = qkn + ((size_t)bf*NN + n0 + lane)*CCH + wave*32;
#pragma unroll
    for (int g = 0; g < 4; ++g) {
        uint4 v;
        uint32 d[4];
#pragma unroll
        for (int j = 0; j < 4; ++j) {
            float f0 = acc[g*8 + 2*j] * f;
            float f1 = acc[g*8 + 2*j + 1] * f;
            d[j] = (uint32)bf16r(f0) | ((uint32)bf16r(f1) << 16);
        }
        v.x = d[0]; v.y = d[1]; v.z = d[2]; v.w = d[3];
        ((uint4*)dst)[g] = v;
    }
}

// ---------------- K5: MFMA flash attention, O bf16 [bf,n,c] ----------------
// XCD-swizzled 1D grid: same-bf tiles stay on one XCD (L2 reuse of K/V).
// Q fragments hoisted to registers; K/V prefetched to regs before the barrier;
// Ps aliases the dead Qs buffer (52KB LDS -> 3 blocks/CU); Ps written as packed b32.
__global__ __launch_bounds__(256, 3) void k_attn(const ushort* __restrict__ qkn, const ushort* __restrict__ Vt_g,
                                                 ushort* __restrict__ Ob) {
    __shared__ ushort QPs[64*136];     // Qs (stride 136) then Ps (stride 72)
    __shared__ ushort Ks[64*136];
    __shared__ ushort Vs[128*72];
    int id = blockIdx.x;               // 0..1151
    int rem = id >> 3;
    int bf  = ((rem / 9) << 3) | (id & 7);
    int tile = rem % 9;
    int n0 = tile*64;
    int tid = threadIdx.x;
    int wv = tid >> 6, l = tid & 63, quad = l >> 4, l15 = l & 15;
    int qb = wv*16;

    {
        const uint4* qsrc = (const uint4*)(qkn + ((size_t)bf*NN + n0)*CCH);
#pragma unroll
        for (int k = 0; k < 4; ++k) {
            int idx = tid + 256*k;
            int row = idx >> 4, co = idx & 15;
            *(uint4*)&QPs[row*136 + co*8] = qsrc[idx];
        }
    }
    __syncthreads();
    short8 aq[4];
#pragma unroll
    for (int kk = 0; kk < 4; ++kk)
        aq[kk] = *(const short8*)&QPs[(qb + l15)*136 + kk*32 + quad*8];

    floatx4 oacc[8];
#pragma unroll
    for (int ct = 0; ct < 8; ++ct) oacc[ct] = (floatx4){0.f,0.f,0.f,0.f};
    float rsum[4] = {0.f,0.f,0.f,0.f};
    const float scale = 0.08838834764831845f;   // 1/sqrt(128)

    const uint4* vbase = (const uint4*)(Vt_g + (size_t)bf*CCH*NN);   // [c][n/8], 72 uint4 per row

    for (int mt = 0; mt < 9; ++mt) {
        int m0 = mt*64;
        // prefetch to registers (overlaps previous iteration's MFMA)
        uint4 kreg[4], vreg[4];
        {
            const uint4* ksrc = (const uint4*)(qkn + ((size_t)bf*NN + m0)*CCH);
            int mo8 = m0 >> 3;
#pragma unroll
            for (int k = 0; k < 4; ++k) {
                int idx = tid + 256*k;
                kreg[k] = ksrc[idx];
                int c = idx >> 3, ko = idx & 7;
                vreg[k] = vbase[(size_t)c*72 + mo8 + ko];
            }
        }
        __syncthreads();   // prior reads of Ks/Vs complete
#pragma unroll
        for (int k = 0; k < 4; ++k) {
            int idx = tid + 256*k;
            int row = idx >> 4, co = idx & 15;
            *(uint4*)&Ks[row*136 + co*8] = kreg[k];
            int c = idx >> 3, ko = idx & 7;
            *(uint4*)&Vs[c*72 + ko*8] = vreg[k];
        }
        __syncthreads();

        // S = Q K^T
        floatx4 sc[4];
#pragma unroll
        for (int t = 0; t < 4; ++t) sc[t] = (floatx4){0.f,0.f,0.f,0.f};
#pragma unroll
        for (int kk = 0; kk < 4; ++kk)
#pragma unroll
            for (int t = 0; t < 4; ++t) {
                const short8 bk = *(const short8*)&Ks[(t*16 + l15)*136 + kk*32 + quad*8];
                sc[t] = __builtin_amdgcn_mfma_f32_16x16x32_bf16(aq[kk], bk, sc[t], 0, 0, 0);
            }

        // exp + P->LDS (packed b32 via lane-pair shfl) + row-sums
        float pr[4] = {0.f,0.f,0.f,0.f};
#pragma unroll
        for (int t = 0; t < 4; ++t)
#pragma unroll
            for (int r = 0; r < 4; ++r) {
                float p = __expf((sc[t][r] + 1.f)*scale);
                float pn = __shfl_xor(p, 1);
                if ((l15 & 1) == 0)
                    *(uint32*)&QPs[(qb + quad*4 + r)*72 + t*16 + l15] =
                        (uint32)bf16r(p) | ((uint32)bf16r(pn) << 16);
                pr[r] += p;
            }
#pragma unroll
        for (int off = 1; off < 16; off <<= 1)
#pragma unroll
            for (int r = 0; r < 4; ++r) pr[r] += __shfl_xor(pr[r], off);
#pragma unroll
        for (int r = 0; r < 4; ++r) rsum[r] += pr[r];

        // O += P V  (same-wave LDS round-trip, no barrier)
        short8 ap[2];
        ap[0] = *(const short8*)&QPs[(qb + l15)*72 + quad*8];
        ap[1] = *(const short8*)&QPs[(qb + l15)*72 + 32 + quad*8];
#pragma unroll
        for (int ct = 0; ct < 8; ++ct)
#pragma unroll
            for (int kk2 = 0; kk2 < 2; ++kk2) {
                const short8 bv = *(const short8*)&Vs[(ct*16 + l15)*72 + kk2*32 + quad*8];
                oacc[ct] = __builtin_amdgcn_mfma_f32_16x16x32_bf16(ap[kk2], bv, oacc[ct], 0, 0, 0);
            }
    }

    float rinv[4];
#pragma unroll
    for (int r = 0; r < 4; ++r) rinv[r] = 1.f / rsum[r];
#pragma unroll
    for (int ct = 0; ct < 8; ++ct)
#pragma unroll
        for (int r = 0; r < 4; ++r)
            Ob[((size_t)bf*NN + n0 + qb + quad*4 + r)*CCH + ct*16 + l15] = bf16r(oacc[ct][r]*rinv[r]);
}

// ---------------- K6: yb[b][row][ci_oct16][xp196][8ci] (bf16) = x + shuffle(O) ----------------
__global__ __launch_bounds__(256) void k_shuffle_add(const ushort* __restrict__ Ob, const float* __restrict__ x,
                                                     uint4* __restrict__ yb) {
    __shared__ float t[128][65];
    int x0 = blockIdx.x * 64;
    int yy = blockIdx.y;
    int b  = blockIdx.z;
    int i = yy >> 3, dy = yy & 7;
#pragma unroll
    for (int k = 0; k < 32; ++k) {
        int idx = threadIdx.x + 256*k;
        int c = idx & 127, xl = idx >> 7;
        int xx = x0 + xl;
        int j = xx >> 3, dx = xx & 7;
        int bf = (b << 6) + (dy << 3) + dx;
        int n = i*SH + j;
        t[c][xl] = frombf(Ob[((size_t)bf*NN + n)*CCH + c]);
    }
    __syncthreads();
    size_t base = (size_t)b*CHW + (size_t)yy*WW + x0;
#pragma unroll
    for (int k = 0; k < 32; ++k) {
        int idx = threadIdx.x + 256*k;
        int c = idx >> 6, xl = idx & 63;
        t[c][xl] += x[base + (size_t)c*HW + xl];
    }
    __syncthreads();
#pragma unroll
    for (int k = 0; k < 4; ++k) {
        int idx = threadIdx.x + 256*k;
        int xl = idx & 63, oc = idx >> 6;    // oc 0..15 (ci octet)
        uint32 d[4];
#pragma unroll
        for (int j = 0; j < 4; ++j) {
            float f0 = t[oc*8 + 2*j][xl];
            float f1 = t[oc*8 + 2*j + 1][xl];
            d[j] = (uint32)bf16r(f0) | ((uint32)bf16r(f1) << 16);
        }
        uint4 v; v.x = d[0]; v.y = d[1]; v.z = d[2]; v.w = d[3];
        yb[((size_t)(b*192 + yy)*16 + oc)*196 + (x0 + xl + 2)] = v;
    }
}

// ---------------- weight casts ----------------
__global__ __launch_bounds__(256) void k_cast_w(const float* __restrict__ w1, const float* __restrict__ w2,
                                                const float* __restrict__ w3,
                                                uint4* __restrict__ wb1, uint4* __restrict__ wb2,
                                                uint4* __restrict__ w3b) {
    int id = blockIdx.x*256 + threadIdx.x;       // 0..18431
    if (blockIdx.y == 2) {
        if (id < 2048) {
            int co = id >> 4, oct = id & 15;
            uint32 r[4];
#pragma unroll
            for (int j = 0; j < 4; ++j) {
                float f0 = w3[(size_t)co*128 + oct*8 + 2*j];
                float f1 = w3[(size_t)co*128 + oct*8 + 2*j + 1];
                r[j] = (uint32)bf16r(f0) | ((uint32)bf16r(f1) << 16);
            }
            uint4 v; v.x = r[0]; v.y = r[1]; v.z = r[2]; v.w = r[3];
            w3b[id] = v;
        }
        return;
    }
    const float* w = (blockIdx.y == 0) ? w1 : w2;
    uint4* wb = (blockIdx.y == 0) ? wb1 : wb2;
    int co = id & 127;
    int oct = (id >> 7) & 3;
    int chunk = (id >> 9) & 3;
    int tap = id >> 11;                           // 0..8
    int ci0 = chunk*32 + oct*8;
    uint32 r[4];
#pragma unroll
    for (int j = 0; j < 4; ++j) {
        float f0 = w[(size_t)(co*128 + ci0 + 2*j)*9 + tap];
        float f1 = w[(size_t)(co*128 + ci0 + 2*j + 1)*9 + tap];
        r[j] = (uint32)bf16r(f0) | ((uint32)bf16r(f1) << 16);
    }
    uint4 v; v.x = r[0]; v.y = r[1]; v.z = r[2]; v.w = r[3];
    wb[((size_t)(tap*4 + chunk)*4 + oct)*128 + co] = v;
}

// ---------------- K7/K8: 3x3 dilated conv as bf16 MFMA implicit GEMM ----------------
__global__ __launch_bounds__(256, 3) void k_conv3m(const uint4* __restrict__ yb, const uint4* __restrict__ wb,
                                                   const float* __restrict__ bias, void* __restrict__ outp,
                                                   int mode) {
    __shared__ uint4 As[864];          // [r6][oct4][px36] 16B units
    __shared__ uint4 Ws[2][512];       // [oct4][co128]
    int xt = blockIdx.x;               // 0..5
    int rg = blockIdx.y;               // 0..47
    int b  = blockIdx.z;
    int par = rg & 1, g = rg >> 1;
    int y0 = 8*g + par;
    int x0 = xt*32;
    int tid = threadIdx.x;
    int wv = tid >> 6, l = tid & 63, quad = l >> 4, l15 = l & 15;
    int yw = y0 + 2*wv;

    floatx4 acc[2][8];
#pragma unroll
    for (int mt = 0; mt < 2; ++mt)
#pragma unroll
        for (int nt = 0; nt < 8; ++nt) acc[mt][nt] = (floatx4){0.f,0.f,0.f,0.f};

    const uint4* ybb = yb + (size_t)b*602112;   // 192*16*196

    for (int chunk = 0; chunk < 4; ++chunk) {
        __syncthreads();
#pragma unroll
        for (int k = 0; k < 4; ++k) {
            int idx = tid + 256*k;
            if (idx < 864) {
                int r = idx / 144;
                int rem = idx - r*144;
                int oct = rem / 36;
                int px = rem - oct*36;
                int grow = y0 - 2 + 2*r;
                uint4 v; v.x = 0; v.y = 0; v.z = 0; v.w = 0;
                if (grow >= 0 && grow < 192)
                    v = ybb[((size_t)grow*16 + chunk*4 + oct)*196 + x0 + px];
                As[idx] = v;
            }
        }
        {
            const uint4* src = wb + (size_t)chunk*512;
            Ws[0][tid]     = src[tid];
            Ws[0][tid+256] = src[tid+256];
        }
        __syncthreads();
#pragma unroll
        for (int tap = 0; tap < 9; ++tap) {
            if (tap < 8) {
                const uint4* src = wb + (size_t)((tap+1)*4 + chunk)*512;
                Ws[(tap+1)&1][tid]     = src[tid];
                Ws[(tap+1)&1][tid+256] = src[tid+256];
            }
            const int ky = tap/3, kx = tap - 3*(tap/3);
            int r = wv + ky;
            const short8 a0 = *(const short8*)&As[(r*4 + quad)*36 + l15 + 2*kx];
            const short8 a1 = *(const short8*)&As[(r*4 + quad)*36 + 16 + l15 + 2*kx];
            const uint4* wbuf = &Ws[tap&1][0];
#pragma unroll
            for (int nt = 0; nt < 8; ++nt) {
                const short8 bf = *(const short8*)&wbuf[quad*128 + nt*16 + l15];
                acc[0][nt] = __builtin_amdgcn_mfma_f32_16x16x32_bf16(a0, bf, acc[0][nt], 0, 0, 0);
                acc[1][nt] = __builtin_amdgcn_mfma_f32_16x16x32_bf16(a1, bf, acc[1][nt], 0, 0, 0);
            }
            __syncthreads();
        }
    }

    if (mode == 0) {
        unsigned short* outb = (unsigned short*)outp;
#pragma unroll
        for (int nt = 0; nt < 8; ++nt) {
            int co = nt*16 + l15;
            float bv = bias[co];
            size_t base = (((size_t)(b*192 + yw)*16 + ((co>>5)*4 + ((co>>3)&3)))*196)*8 + (size_t)(co&7);
#pragma unroll
            for (int mt = 0; mt < 2; ++mt)
#pragma unroll
                for (int rr = 0; rr < 4; ++rr) {
                    int xx = x0 + mt*16 + quad*4 + rr;
                    float v = fmaxf(acc[mt][nt][rr] + bv, 0.f);
                    outb[base + (size_t)(xx+2)*8] = bf16r(v);
                }
        }
    } else {
        unsigned short* outb = (unsigned short*)outp;   // flat NHWC bf16 [b][px][128]
#pragma unroll
        for (int nt = 0; nt < 8; ++nt) {
            int co = nt*16 + l15;
            float bv = bias[co];
#pragma unroll
            for (int mt = 0; mt < 2; ++mt)
#pragma unroll
                for (int rr = 0; rr < 4; ++rr) {
                    int xx = x0 + mt*16 + quad*4 + rr;
                    float v = fmaxf(acc[mt][nt][rr] + bv, 0.f);
                    outb[((size_t)b*36864 + (size_t)yw*192 + xx)*128 + co] = bf16r(v);
                }
        }
    }
}

// ---------------- K9: out = x + (w3 @ h2b) + b3 via MFMA, h2b bf16 NHWC ----------------
__global__ __launch_bounds__(256, 2) void k_conv1x1m(const ushort* __restrict__ h2b, const uint4* __restrict__ w3b,
                                                     const float* __restrict__ b3, const float* __restrict__ x,
                                                     float* __restrict__ out) {
    __shared__ ushort Hs[128*136];
    __shared__ ushort Ws3[128*136];
    int px0 = blockIdx.x * 128;
    int b = blockIdx.y;
    int tid = threadIdx.x;
    int wv = tid >> 6, l = tid & 63, quad = l >> 4, l15 = l & 15;

    {
        const uint4* hsrc = (const uint4*)(h2b + ((size_t)b*36864 + px0)*128);
#pragma unroll
        for (int k = 0; k < 8; ++k) {
            int idx = tid + 256*k;
            int row = idx >> 4, co8 = idx & 15;
            *(uint4*)&Hs[row*136 + co8*8] = hsrc[idx];
            *(uint4*)&Ws3[row*136 + co8*8] = w3b[idx];
        }
    }
    __syncthreads();

    floatx4 oacc[2][8];
#pragma unroll
    for (int mt = 0; mt < 2; ++mt)
#pragma unroll
        for (int nt = 0; nt < 8; ++nt) oacc[mt][nt] = (floatx4){0.f,0.f,0.f,0.f};

#pragma unroll
    for (int kk = 0; kk < 4; ++kk) {
        const short8 aq0 = *(const short8*)&Hs[(wv*32 + l15)*136 + kk*32 + quad*8];
        const short8 aq1 = *(const short8*)&Hs[(wv*32 + 16 + l15)*136 + kk*32 + quad*8];
#pragma unroll
        for (int nt = 0; nt < 8; ++nt) {
            const short8 bw = *(const short8*)&Ws3[(nt*16 + l15)*136 + kk*32 + quad*8];
            oacc[0][nt] = __builtin_amdgcn_mfma_f32_16x16x32_bf16(aq0, bw, oacc[0][nt], 0, 0, 0);
            oacc[1][nt] = __builtin_amdgcn_mfma_f32_16x16x32_bf16(aq1, bw, oacc[1][nt], 0, 0, 0);
        }
    }

#pragma unroll
    for (int nt = 0; nt < 8; ++nt) {
        int co = nt*16 + l15;
        float bv = b3[co];
        size_t pbase = ((size_t)b*128 + co)*HW + px0 + wv*32 + quad*4;
#pragma unroll
        for (int mt = 0; mt < 2; ++mt) {
            const float4 xv = *(const float4*)&x[pbase + mt*16];
            float4 o;
            o.x = oacc[mt][nt][0] + bv + xv.x;
            o.y = oacc[mt][nt][1] + bv + xv.y;
            o.z = oacc[mt][nt][2] + bv + xv.z;
            o.w = oacc[mt][nt][3] + bv + xv.w;
            *(float4*)&out[pbase + mt*16] = o;
        }
    }
}

extern "C" void kernel_launch(void* const* d_in, const int* in_sizes, int n_in,
                              void* d_out, int out_size, void* d_ws, size_t ws_size,
                              hipStream_t stream) {
    (void)in_sizes; (void)n_in; (void)out_size; (void)ws_size;
    const float* x   = (const float*)d_in[0];
    const float* wqk = (const float*)d_in[1];
    const float* w1  = (const float*)d_in[2];
    const float* b1  = (const float*)d_in[3];
    const float* w2  = (const float*)d_in[4];
    const float* b2  = (const float*)d_in[5];
    const float* w3  = (const float*)d_in[6];
    const float* b3  = (const float*)d_in[7];
    float* out = (float*)d_out;
    char* ws = (char*)d_ws;
    float* stats = (float*)ws;
    const size_t SZ = (size_t)BF * NN * CCH * sizeof(float);   // 37,748,736 B
    const size_t YBSZ = (size_t)2*192*16*196*16;               // 19,267,584 B
    char* Abase = ws + 256;
    char* Bbase = ws + 256 + SZ;
    char* Cbase = ws + 256 + 2*SZ;
    ushort* Vt  = (ushort*)Abase;
    float*  Xn  = (float*)Bbase;
    ushort* qkn = (ushort*)Cbase;
    ushort* Ob  = (ushort*)Bbase;      // bf16 O, 18.9 MB
    uint4*  yb  = (uint4*)Cbase;
    uint4*  h1b = (uint4*)Abase;
    ushort* h2b = (ushort*)(Bbase + 18874368);   // bf16 NHWC flat, 18.9 MB (after Ob)
    uint4* wb1 = (uint4*)(Abase + 20*1024*1024);
    uint4* wb2 = (uint4*)(Abase + 21*1024*1024);
    uint4* w3b = (uint4*)(Abase + 22*1024*1024);

    hipMemsetAsync(stats, 0, 4*sizeof(float), stream);
    k_reduce     <<<dim3(288, 2),     256, 0, stream>>>(x, stats);
    k_finalize   <<<1, 64,            0, stream>>>(stats);
    k_unshuffle  <<<dim3(3, 192, 2),  256, 0, stream>>>(x, stats, Vt, Xn);
    k_qk         <<<1152,             256, 0, stream>>>(Xn, wqk, qkn);
    k_attn       <<<1152,             256, 0, stream>>>(qkn, Vt, Ob);
    hipMemsetAsync(yb,  0, YBSZ, stream);
    hipMemsetAsync(h1b, 0, YBSZ, stream);
    k_cast_w     <<<dim3(72, 3),      256, 0, stream>>>(w1, w2, w3, wb1, wb2, w3b);
    k_shuffle_add<<<dim3(3, 192, 2),  256, 0, stream>>>(Ob, x, yb);
    k_conv3m     <<<dim3(6, 48, 2),   256, 0, stream>>>(yb,  wb1, b1, (void*)h1b, 0);
    k_conv3m     <<<dim3(6, 48, 2),   256, 0, stream>>>(h1b, wb2, b2, (void*)h2b, 1);
    k_conv1x1m   <<<dim3(288, 2),     256, 0, stream>>>(h2b, w3b, b3, x, out);
}

// Round 7
// 451.241 us; speedup vs baseline: 1.0215x; 1.0215x over previous
//
#include <hip/hip_runtime.h>
#include <math.h>

#define CCH 128
#define HH 192
#define WW 192
#define BB 2
#define HW (HH*WW)        // 36864
#define CHW (CCH*HW)      // 4718592
#define BF 128            // B * f*f = 2*64
#define NN 576            // 24*24
#define SH 24

typedef __attribute__((ext_vector_type(8))) short short8;
typedef __attribute__((ext_vector_type(4))) float floatx4;
typedef unsigned int uint32;
typedef unsigned short ushort;

__device__ __forceinline__ unsigned short bf16r(float f) {
    uint32 u = __float_as_uint(f);
    u += 0x7fffu + ((u >> 16) & 1u);
    return (unsigned short)(u >> 16);
}
__device__ __forceinline__ float frombf(ushort u) {
    return __uint_as_float(((uint32)u) << 16);
}

// ---------------- K1: per-batch sum / sumsq reduction ----------------
__global__ __launch_bounds__(256) void k_reduce(const float* __restrict__ x, float* __restrict__ stats) {
    int b = blockIdx.y;
    const float4* p = (const float4*)(x + (size_t)b*CHW) + (size_t)blockIdx.x*4096;
    float s = 0.f, sq = 0.f;
#pragma unroll
    for (int k = 0; k < 16; ++k) {
        float4 v = p[threadIdx.x + 256*k];
        s  += v.x + v.y + v.z + v.w;
        sq += v.x*v.x + v.y*v.y + v.z*v.z + v.w*v.w;
    }
    for (int off = 32; off; off >>= 1) { s += __shfl_down(s, off); sq += __shfl_down(sq, off); }
    __shared__ float ls[4], lq[4];
    int wave = threadIdx.x >> 6, lane = threadIdx.x & 63;
    if (lane == 0) { ls[wave] = s; lq[wave] = sq; }
    __syncthreads();
    if (threadIdx.x == 0) {
        atomicAdd(&stats[2*b],   ls[0]+ls[1]+ls[2]+ls[3]);
        atomicAdd(&stats[2*b+1], lq[0]+lq[1]+lq[2]+lq[3]);
    }
}

__global__ void k_finalize(float* stats) {
    int b = threadIdx.x;
    if (b < BB) {
        float s = stats[2*b], sq = stats[2*b+1];
        float mean = s / (float)CHW;
        float var = sq / (float)CHW - mean*mean;
        stats[4 + 2*b] = mean;
        stats[5 + 2*b] = rsqrtf(var + 1e-5f);
    }
}

// ---------------- K3: x -> V_t bf16 [Bf,C,N] and Xn fp32 [Bf,N,C] ----------------
__global__ __launch_bounds__(256) void k_unshuffle(const float* __restrict__ x, const float* __restrict__ stats,
                                                   ushort* __restrict__ Vt, float* __restrict__ Xn) {
    __shared__ float t[128][65];
    int x0 = blockIdx.x * 64;
    int y  = blockIdx.y;
    int b  = blockIdx.z;
    float mean = stats[4+2*b], istd = stats[5+2*b];
    const float* src = x + (size_t)b*CHW + (size_t)y*WW + x0;
#pragma unroll
    for (int k = 0; k < 32; ++k) {
        int idx = threadIdx.x + 256*k;
        int c = idx >> 6, xl = idx & 63;
        t[c][xl] = src[(size_t)c*HW + xl];
    }
    __syncthreads();
    int i = y >> 3, dy = y & 7;
#pragma unroll
    for (int k = 0; k < 32; ++k) {
        int idx = threadIdx.x + 256*k;
        int c = idx & 127, xl = idx >> 7;
        int xx = x0 + xl;
        int j = xx >> 3, dx = xx & 7;
        int bf = (b << 6) + (dy << 3) + dx;
        int n = i*SH + j;
        float v = t[c][xl];
        Vt[((size_t)bf*CCH + c)*NN + n] = bf16r(v);
        Xn[((size_t)bf*NN + n)*CCH + c] = (v - mean) * istd;
    }
}

// ---------------- K4: qkn(bf16) = normalize_rows(Xn @ wqk) ----------------
__global__ __launch_bounds__(256) void k_qk(const float* __restrict__ Xn, const float* __restrict__ wqk,
                                            ushort* __restrict__ qkn) {
    __shared__ float Qs[64][129];
    __shared__ float ssb[64][4];
    int bid = blockIdx.x;           // 0..1151
    int bf = bid / 9, tile = bid % 9;
    int n0 = tile * 64;
    const float* src = Xn + ((size_t)bf*NN + n0)*CCH;
#pragma unroll
    for (int k = 0; k < 32; ++k) {
        int idx = threadIdx.x + 256*k;
        Qs[idx >> 7][idx & 127] = src[idx];
    }
    __syncthreads();
    int lane = threadIdx.x & 63;
    int wave = __builtin_amdgcn_readfirstlane(threadIdx.x >> 6);
    float acc[32];
#pragma unroll
    for (int k = 0; k < 32; ++k) acc[k] = 0.f;
    const float* wp = wqk + wave*32;
    for (int c = 0; c < 128; ++c) {
        float qv = Qs[lane][c];
#pragma unroll
        for (int k = 0; k < 32; ++k) acc[k] += qv * wp[c*128 + k];
    }
    float ss = 0.f;
#pragma unroll
    for (int k = 0; k < 32; ++k) ss += acc[k]*acc[k];
    ssb[lane][wave] = ss;
    __syncthreads();
    float tot = ssb[lane][0]+ssb[lane][1]+ssb[lane][2]+ssb[lane][3];
    float f = 1.f / (sqrtf(tot) + 1e-8f);
    ushort* dst = qkn + ((size_t)bf*NN + n0 + lane)*CCH + wave*32;
#pragma unroll
    for (int g = 0; g < 4; ++g) {
        uint4 v;
        uint32 d[4];
#pragma unroll
        for (int j = 0; j < 4; ++j) {
            float f0 = acc[g*8 + 2*j] * f;
            float f1 = acc[g*8 + 2*j + 1] * f;
            d[j] = (uint32)bf16r(f0) | ((uint32)bf16r(f1) << 16);
        }
        v.x = d[0]; v.y = d[1]; v.z = d[2]; v.w = d[3];
        ((uint4*)dst)[g] = v;
    }
}

// ---------------- K5: MFMA flash attention, O bf16 [bf,n,c] ----------------
// XCD-swizzled 1D grid (FETCH 155->49MB verified R6). Q frags hoisted; K/V reg-prefetch.
// Epilogue: O staged through dead Ks buffer -> lane-contiguous uint4 stores
// (R6's scattered 2B stores caused 288MB WRITE_SIZE, 15x amplification).
__global__ __launch_bounds__(256, 3) void k_attn(const ushort* __restrict__ qkn, const ushort* __restrict__ Vt_g,
                                                 ushort* __restrict__ Ob) {
    __shared__ ushort QPs[64*136];     // Qs (stride 136) then Ps (stride 72)
    __shared__ ushort Ks[64*136];      // K tiles; after loop: O staging (stride 132)
    __shared__ ushort Vs[128*72];
    int id = blockIdx.x;               // 0..1151
    int rem = id >> 3;
    int bf  = ((rem / 9) << 3) | (id & 7);
    int tile = rem % 9;
    int n0 = tile*64;
    int tid = threadIdx.x;
    int wv = tid >> 6, l = tid & 63, quad = l >> 4, l15 = l & 15;
    int qb = wv*16;

    {
        const uint4* qsrc = (const uint4*)(qkn + ((size_t)bf*NN + n0)*CCH);
#pragma unroll
        for (int k = 0; k < 4; ++k) {
            int idx = tid + 256*k;
            int row = idx >> 4, co = idx & 15;
            *(uint4*)&QPs[row*136 + co*8] = qsrc[idx];
        }
    }
    __syncthreads();
    short8 aq[4];
#pragma unroll
    for (int kk = 0; kk < 4; ++kk)
        aq[kk] = *(const short8*)&QPs[(qb + l15)*136 + kk*32 + quad*8];

    floatx4 oacc[8];
#pragma unroll
    for (int ct = 0; ct < 8; ++ct) oacc[ct] = (floatx4){0.f,0.f,0.f,0.f};
    float rsum[4] = {0.f,0.f,0.f,0.f};
    const float scale = 0.08838834764831845f;   // 1/sqrt(128)

    const uint4* vbase = (const uint4*)(Vt_g + (size_t)bf*CCH*NN);   // [c][n/8], 72 uint4 per row

    for (int mt = 0; mt < 9; ++mt) {
        int m0 = mt*64;
        // prefetch to registers (overlaps previous iteration's MFMA)
        uint4 kreg[4], vreg[4];
        {
            const uint4* ksrc = (const uint4*)(qkn + ((size_t)bf*NN + m0)*CCH);
            int mo8 = m0 >> 3;
#pragma unroll
            for (int k = 0; k < 4; ++k) {
                int idx = tid + 256*k;
                kreg[k] = ksrc[idx];
                int c = idx >> 3, ko = idx & 7;
                vreg[k] = vbase[(size_t)c*72 + mo8 + ko];
            }
        }
        __syncthreads();   // prior reads of Ks/Vs complete
#pragma unroll
        for (int k = 0; k < 4; ++k) {
            int idx = tid + 256*k;
            int row = idx >> 4, co = idx & 15;
            *(uint4*)&Ks[row*136 + co*8] = kreg[k];
            int c = idx >> 3, ko = idx & 7;
            *(uint4*)&Vs[c*72 + ko*8] = vreg[k];
        }
        __syncthreads();

        // S = Q K^T
        floatx4 sc[4];
#pragma unroll
        for (int t = 0; t < 4; ++t) sc[t] = (floatx4){0.f,0.f,0.f,0.f};
#pragma unroll
        for (int kk = 0; kk < 4; ++kk)
#pragma unroll
            for (int t = 0; t < 4; ++t) {
                const short8 bk = *(const short8*)&Ks[(t*16 + l15)*136 + kk*32 + quad*8];
                sc[t] = __builtin_amdgcn_mfma_f32_16x16x32_bf16(aq[kk], bk, sc[t], 0, 0, 0);
            }

        // exp + P->LDS (2B writes, 2 lanes/dword = free) + row-sums
        float pr[4] = {0.f,0.f,0.f,0.f};
#pragma unroll
        for (int t = 0; t < 4; ++t)
#pragma unroll
            for (int r = 0; r < 4; ++r) {
                float p = __expf((sc[t][r] + 1.f)*scale);
                QPs[(qb + quad*4 + r)*72 + t*16 + l15] = bf16r(p);
                pr[r] += p;
            }
#pragma unroll
        for (int off = 1; off < 16; off <<= 1)
#pragma unroll
            for (int r = 0; r < 4; ++r) pr[r] += __shfl_xor(pr[r], off);
#pragma unroll
        for (int r = 0; r < 4; ++r) rsum[r] += pr[r];

        // O += P V  (same-wave LDS round-trip, no barrier)
        short8 ap[2];
        ap[0] = *(const short8*)&QPs[(qb + l15)*72 + quad*8];
        ap[1] = *(const short8*)&QPs[(qb + l15)*72 + 32 + quad*8];
#pragma unroll
        for (int ct = 0; ct < 8; ++ct)
#pragma unroll
            for (int kk2 = 0; kk2 < 2; ++kk2) {
                const short8 bv = *(const short8*)&Vs[(ct*16 + l15)*72 + kk2*32 + quad*8];
                oacc[ct] = __builtin_amdgcn_mfma_f32_16x16x32_bf16(ap[kk2], bv, oacc[ct], 0, 0, 0);
            }
    }

    // epilogue: stage O tile in Ks (dead), then contiguous uint4 global stores
    __syncthreads();   // all waves done reading Ks
    float rinv[4];
#pragma unroll
    for (int r = 0; r < 4; ++r) rinv[r] = 1.f / rsum[r];
    ushort* Obuf = Ks;               // stride 132 (64*132 = 8448 <= 64*136)
#pragma unroll
    for (int ct = 0; ct < 8; ++ct)
#pragma unroll
        for (int r = 0; r < 4; ++r)
            Obuf[(qb + quad*4 + r)*132 + ct*16 + l15] = bf16r(oacc[ct][r]*rinv[r]);
    // same-wave read-back: wave wv wrote rows qb..qb+15 and reads only those rows
    uint4* Obg = (uint4*)(Ob + ((size_t)bf*NN + n0)*CCH);
#pragma unroll
    for (int k = 0; k < 4; ++k) {
        int f = k*64 + l;            // 0..255 within wave's 16 rows x 16 uint4
        int row = f >> 4, colu = f & 15;
        uint4 v = *(const uint4*)&Obuf[(qb + row)*132 + colu*8];
        Obg[qb*16 + f] = v;
    }
}

// ---------------- K6: yb[b][row][ci_oct16][xp196][8ci] (bf16) = x + shuffle(O) ----------------
__global__ __launch_bounds__(256) void k_shuffle_add(const ushort* __restrict__ Ob, const float* __restrict__ x,
                                                     uint4* __restrict__ yb) {
    __shared__ float t[128][65];
    int x0 = blockIdx.x * 64;
    int yy = blockIdx.y;
    int b  = blockIdx.z;
    int i = yy >> 3, dy = yy & 7;
#pragma unroll
    for (int k = 0; k < 32; ++k) {
        int idx = threadIdx.x + 256*k;
        int c = idx & 127, xl = idx >> 7;
        int xx = x0 + xl;
        int j = xx >> 3, dx = xx & 7;
        int bf = (b << 6) + (dy << 3) + dx;
        int n = i*SH + j;
        t[c][xl] = frombf(Ob[((size_t)bf*NN + n)*CCH + c]);
    }
    __syncthreads();
    size_t base = (size_t)b*CHW + (size_t)yy*WW + x0;
#pragma unroll
    for (int k = 0; k < 32; ++k) {
        int idx = threadIdx.x + 256*k;
        int c = idx >> 6, xl = idx & 63;
        t[c][xl] += x[base + (size_t)c*HW + xl];
    }
    __syncthreads();
#pragma unroll
    for (int k = 0; k < 4; ++k) {
        int idx = threadIdx.x + 256*k;
        int xl = idx & 63, oc = idx >> 6;    // oc 0..15 (ci octet)
        uint32 d[4];
#pragma unroll
        for (int j = 0; j < 4; ++j) {
            float f0 = t[oc*8 + 2*j][xl];
            float f1 = t[oc*8 + 2*j + 1][xl];
            d[j] = (uint32)bf16r(f0) | ((uint32)bf16r(f1) << 16);
        }
        uint4 v; v.x = d[0]; v.y = d[1]; v.z = d[2]; v.w = d[3];
        yb[((size_t)(b*192 + yy)*16 + oc)*196 + (x0 + xl + 2)] = v;
    }
}

// ---------------- weight casts ----------------
__global__ __launch_bounds__(256) void k_cast_w(const float* __restrict__ w1, const float* __restrict__ w2,
                                                const float* __restrict__ w3,
                                                uint4* __restrict__ wb1, uint4* __restrict__ wb2,
                                                uint4* __restrict__ w3b) {
    int id = blockIdx.x*256 + threadIdx.x;       // 0..18431
    if (blockIdx.y == 2) {
        if (id < 2048) {
            int co = id >> 4, oct = id & 15;
            uint32 r[4];
#pragma unroll
            for (int j = 0; j < 4; ++j) {
                float f0 = w3[(size_t)co*128 + oct*8 + 2*j];
                float f1 = w3[(size_t)co*128 + oct*8 + 2*j + 1];
                r[j] = (uint32)bf16r(f0) | ((uint32)bf16r(f1) << 16);
            }
            uint4 v; v.x = r[0]; v.y = r[1]; v.z = r[2]; v.w = r[3];
            w3b[id] = v;
        }
        return;
    }
    const float* w = (blockIdx.y == 0) ? w1 : w2;
    uint4* wb = (blockIdx.y == 0) ? wb1 : wb2;
    int co = id & 127;
    int oct = (id >> 7) & 3;
    int chunk = (id >> 9) & 3;
    int tap = id >> 11;                           // 0..8
    int ci0 = chunk*32 + oct*8;
    uint32 r[4];
#pragma unroll
    for (int j = 0; j < 4; ++j) {
        float f0 = w[(size_t)(co*128 + ci0 + 2*j)*9 + tap];
        float f1 = w[(size_t)(co*128 + ci0 + 2*j + 1)*9 + tap];
        r[j] = (uint32)bf16r(f0) | ((uint32)bf16r(f1) << 16);
    }
    uint4 v; v.x = r[0]; v.y = r[1]; v.z = r[2]; v.w = r[3];
    wb[((size_t)(tap*4 + chunk)*4 + oct)*128 + co] = v;
}

// ---------------- K7/K8: 3x3 dilated conv as bf16 MFMA implicit GEMM ----------------
__global__ __launch_bounds__(256, 3) void k_conv3m(const uint4* __restrict__ yb, const uint4* __restrict__ wb,
                                                   const float* __restrict__ bias, void* __restrict__ outp,
                                                   int mode) {
    __shared__ uint4 As[864];          // [r6][oct4][px36] 16B units
    __shared__ uint4 Ws[2][512];       // [oct4][co128]
    int xt = blockIdx.x;               // 0..5
    int rg = blockIdx.y;               // 0..47
    int b  = blockIdx.z;
    int par = rg & 1, g = rg >> 1;
    int y0 = 8*g + par;
    int x0 = xt*32;
    int tid = threadIdx.x;
    int wv = tid >> 6, l = tid & 63, quad = l >> 4, l15 = l & 15;
    int yw = y0 + 2*wv;

    floatx4 acc[2][8];
#pragma unroll
    for (int mt = 0; mt < 2; ++mt)
#pragma unroll
        for (int nt = 0; nt < 8; ++nt) acc[mt][nt] = (floatx4){0.f,0.f,0.f,0.f};

    const uint4* ybb = yb + (size_t)b*602112;   // 192*16*196

    for (int chunk = 0; chunk < 4; ++chunk) {
        __syncthreads();
#pragma unroll
        for (int k = 0; k < 4; ++k) {
            int idx = tid + 256*k;
            if (idx < 864) {
                int r = idx / 144;
                int rem = idx - r*144;
                int oct = rem / 36;
                int px = rem - oct*36;
                int grow = y0 - 2 + 2*r;
                uint4 v; v.x = 0; v.y = 0; v.z = 0; v.w = 0;
                if (grow >= 0 && grow < 192)
                    v = ybb[((size_t)grow*16 + chunk*4 + oct)*196 + x0 + px];
                As[idx] = v;
            }
        }
        {
            const uint4* src = wb + (size_t)chunk*512;
            Ws[0][tid]     = src[tid];
            Ws[0][tid+256] = src[tid+256];
        }
        __syncthreads();
#pragma unroll
        for (int tap = 0; tap < 9; ++tap) {
            if (tap < 8) {
                const uint4* src = wb + (size_t)((tap+1)*4 + chunk)*512;
                Ws[(tap+1)&1][tid]     = src[tid];
                Ws[(tap+1)&1][tid+256] = src[tid+256];
            }
            const int ky = tap/3, kx = tap - 3*(tap/3);
            int r = wv + ky;
            const short8 a0 = *(const short8*)&As[(r*4 + quad)*36 + l15 + 2*kx];
            const short8 a1 = *(const short8*)&As[(r*4 + quad)*36 + 16 + l15 + 2*kx];
            const uint4* wbuf = &Ws[tap&1][0];
#pragma unroll
            for (int nt = 0; nt < 8; ++nt) {
                const short8 bf = *(const short8*)&wbuf[quad*128 + nt*16 + l15];
                acc[0][nt] = __builtin_amdgcn_mfma_f32_16x16x32_bf16(a0, bf, acc[0][nt], 0, 0, 0);
                acc[1][nt] = __builtin_amdgcn_mfma_f32_16x16x32_bf16(a1, bf, acc[1][nt], 0, 0, 0);
            }
            __syncthreads();
        }
    }

    if (mode == 0) {
        unsigned short* outb = (unsigned short*)outp;
#pragma unroll
        for (int nt = 0; nt < 8; ++nt) {
            int co = nt*16 + l15;
            float bv = bias[co];
            size_t base = (((size_t)(b*192 + yw)*16 + ((co>>5)*4 + ((co>>3)&3)))*196)*8 + (size_t)(co&7);
#pragma unroll
            for (int mt = 0; mt < 2; ++mt)
#pragma unroll
                for (int rr = 0; rr < 4; ++rr) {
                    int xx = x0 + mt*16 + quad*4 + rr;
                    float v = fmaxf(acc[mt][nt][rr] + bv, 0.f);
                    outb[base + (size_t)(xx+2)*8] = bf16r(v);
                }
        }
    } else {
        unsigned short* outb = (unsigned short*)outp;   // flat NHWC bf16 [b][px][128]
#pragma unroll
        for (int nt = 0; nt < 8; ++nt) {
            int co = nt*16 + l15;
            float bv = bias[co];
#pragma unroll
            for (int mt = 0; mt < 2; ++mt)
#pragma unroll
                for (int rr = 0; rr < 4; ++rr) {
                    int xx = x0 + mt*16 + quad*4 + rr;
                    float v = fmaxf(acc[mt][nt][rr] + bv, 0.f);
                    outb[((size_t)b*36864 + (size_t)yw*192 + xx)*128 + co] = bf16r(v);
                }
        }
    }
}

// ---------------- K9: out = x + (w3 @ h2b) + b3 via MFMA, h2b bf16 NHWC ----------------
__global__ __launch_bounds__(256, 2) void k_conv1x1m(const ushort* __restrict__ h2b, const uint4* __restrict__ w3b,
                                                     const float* __restrict__ b3, const float* __restrict__ x,
                                                     float* __restrict__ out) {
    __shared__ ushort Hs[128*136];
    __shared__ ushort Ws3[128*136];
    int px0 = blockIdx.x * 128;
    int b = blockIdx.y;
    int tid = threadIdx.x;
    int wv = tid >> 6, l = tid & 63, quad = l >> 4, l15 = l & 15;

    {
        const uint4* hsrc = (const uint4*)(h2b + ((size_t)b*36864 + px0)*128);
#pragma unroll
        for (int k = 0; k < 8; ++k) {
            int idx = tid + 256*k;
            int row = idx >> 4, co8 = idx & 15;
            *(uint4*)&Hs[row*136 + co8*8] = hsrc[idx];
            *(uint4*)&Ws3[row*136 + co8*8] = w3b[idx];
        }
    }
    __syncthreads();

    floatx4 oacc[2][8];
#pragma unroll
    for (int mt = 0; mt < 2; ++mt)
#pragma unroll
        for (int nt = 0; nt < 8; ++nt) oacc[mt][nt] = (floatx4){0.f,0.f,0.f,0.f};

#pragma unroll
    for (int kk = 0; kk < 4; ++kk) {
        const short8 aq0 = *(const short8*)&Hs[(wv*32 + l15)*136 + kk*32 + quad*8];
        const short8 aq1 = *(const short8*)&Hs[(wv*32 + 16 + l15)*136 + kk*32 + quad*8];
#pragma unroll
        for (int nt = 0; nt < 8; ++nt) {
            const short8 bw = *(const short8*)&Ws3[(nt*16 + l15)*136 + kk*32 + quad*8];
            oacc[0][nt] = __builtin_amdgcn_mfma_f32_16x16x32_bf16(aq0, bw, oacc[0][nt], 0, 0, 0);
            oacc[1][nt] = __builtin_amdgcn_mfma_f32_16x16x32_bf16(aq1, bw, oacc[1][nt], 0, 0, 0);
        }
    }

#pragma unroll
    for (int nt = 0; nt < 8; ++nt) {
        int co = nt*16 + l15;
        float bv = b3[co];
        size_t pbase = ((size_t)b*128 + co)*HW + px0 + wv*32 + quad*4;
#pragma unroll
        for (int mt = 0; mt < 2; ++mt) {
            const float4 xv = *(const float4*)&x[pbase + mt*16];
            float4 o;
            o.x = oacc[mt][nt][0] + bv + xv.x;
            o.y = oacc[mt][nt][1] + bv + xv.y;
            o.z = oacc[mt][nt][2] + bv + xv.z;
            o.w = oacc[mt][nt][3] + bv + xv.w;
            *(float4*)&out[pbase + mt*16] = o;
        }
    }
}

extern "C" void kernel_launch(void* const* d_in, const int* in_sizes, int n_in,
                              void* d_out, int out_size, void* d_ws, size_t ws_size,
                              hipStream_t stream) {
    (void)in_sizes; (void)n_in; (void)out_size; (void)ws_size;
    const float* x   = (const float*)d_in[0];
    const float* wqk = (const float*)d_in[1];
    const float* w1  = (const float*)d_in[2];
    const float* b1  = (const float*)d_in[3];
    const float* w2  = (const float*)d_in[4];
    const float* b2  = (const float*)d_in[5];
    const float* w3  = (const float*)d_in[6];
    const float* b3  = (const float*)d_in[7];
    float* out = (float*)d_out;
    char* ws = (char*)d_ws;
    float* stats = (float*)ws;
    const size_t SZ = (size_t)BF * NN * CCH * sizeof(float);   // 37,748,736 B
    const size_t YBSZ = (size_t)2*192*16*196*16;               // 19,267,584 B
    char* Abase = ws + 256;
    char* Bbase = ws + 256 + SZ;
    char* Cbase = ws + 256 + 2*SZ;
    ushort* Vt  = (ushort*)Abase;
    float*  Xn  = (float*)Bbase;
    ushort* qkn = (ushort*)Cbase;
    ushort* Ob  = (ushort*)Bbase;      // bf16 O, 18.9 MB
    uint4*  yb  = (uint4*)Cbase;
    uint4*  h1b = (uint4*)Abase;
    ushort* h2b = (ushort*)(Bbase + 18874368);   // bf16 NHWC flat, 18.9 MB (after Ob)
    uint4* wb1 = (uint4*)(Abase + 20*1024*1024);
    uint4* wb2 = (uint4*)(Abase + 21*1024*1024);
    uint4* w3b = (uint4*)(Abase + 22*1024*1024);

    hipMemsetAsync(stats, 0, 4*sizeof(float), stream);
    k_reduce     <<<dim3(288, 2),     256, 0, stream>>>(x, stats);
    k_finalize   <<<1, 64,            0, stream>>>(stats);
    k_unshuffle  <<<dim3(3, 192, 2),  256, 0, stream>>>(x, stats, Vt, Xn);
    k_qk         <<<1152,             256, 0, stream>>>(Xn, wqk, qkn);
    k_attn       <<<1152,             256, 0, stream>>>(qkn, Vt, Ob);
    hipMemsetAsync(yb,  0, YBSZ, stream);
    hipMemsetAsync(h1b, 0, YBSZ, stream);
    k_cast_w     <<<dim3(72, 3),      256, 0, stream>>>(w1, w2, w3, wb1, wb2, w3b);
    k_shuffle_add<<<dim3(3, 192, 2),  256, 0, stream>>>(Ob, x, yb);
    k_conv3m     <<<dim3(6, 48, 2),   256, 0, stream>>>(yb,  wb1, b1, (void*)h1b, 0);
    k_conv3m     <<<dim3(6, 48, 2),   256, 0, stream>>>(h1b, wb2, b2, (void*)h2b, 1);
    k_conv1x1m   <<<dim3(288, 2),     256, 0, stream>>>(h2b, w3b, b3, x, out);
}